// Round 14
// baseline (382.761 us; speedup 1.0000x reference)
//
#include <hip/hip_runtime.h>
#include <hip/hip_bf16.h>

#define D 128    // feature dim (both in and out)
#define ELLW 64  // fixed ELL width; Poisson(16) max degree over 50K nodes << 64
#define BCAP 8192  // edges per 256-node bucket region; E[edges]=4096, +64 sigma
#define GRID_FUSED 500  // <= 512 (2 blocks/CU capacity) -> all blocks co-resident; slack for safety

typedef short bf16x8 __attribute__((ext_vector_type(8)));
typedef float f32x4 __attribute__((ext_vector_type(4)));

__device__ __forceinline__ ushort f32_to_bf16_rne(float f) {
    uint b = __float_as_uint(f);
    b += 0x7fffu + ((b >> 16) & 1u);
    return (ushort)(b >> 16);
}
__device__ __forceinline__ float blo(uint u) { return __uint_as_float(u << 16); }
__device__ __forceinline__ float bhi(uint u) { return __uint_as_float(u & 0xffff0000u); }

// ---------------- tiny zero: bcnt[256] + bn_sums[256] + counter (contiguous) ----------------

__global__ __launch_bounds__(768) void zero_kernel(int* __restrict__ p) {
    p[threadIdx.x] = 0;
}

// ------- fused prep+scatter: x->bf16 (into d_out!) | W^T bf16 | bucket scatter -------

__global__ __launch_bounds__(1024) void prep_scatter_kernel(const float2* __restrict__ x2,
                                                            const float* __restrict__ W1,
                                                            const float* __restrict__ W2,
                                                            const int* __restrict__ src,
                                                            const int* __restrict__ dst,
                                                            uint* __restrict__ xb,
                                                            ushort* __restrict__ W1T,
                                                            ushort* __restrict__ W2T,
                                                            uint* __restrict__ part,
                                                            int* __restrict__ bcnt,
                                                            int nhalf, int m, int nbx) {
    int b = blockIdx.x, t = threadIdx.x;
    if (b < nbx) {
        int i = b * 1024 + t;
        if (i < nhalf) {
            float2 v = x2[i];
            xb[i] = ((uint)f32_to_bf16_rne(v.y) << 16) | (uint)f32_to_bf16_rne(v.x);
        }
        return;
    }
    if (b < nbx + 32) {
        int wb = b - nbx;
        const float* W = (wb < 16) ? W1 : W2;
        ushort* WT = (wb < 16) ? W1T : W2T;
        int q = wb & 15;
        int nrow = q * 8 + (t >> 7);
        int k = t & 127;
        WT[nrow * D + k] = f32_to_bf16_rne(W[k * D + nrow]);
        return;
    }
    __shared__ int hist[256];
    __shared__ int cur[256];
    if (t < 256) hist[t] = 0;
    __syncthreads();

    int base = (b - nbx - 32) * 4096;
    uint v[4];
    int bk[4];
    bool ok[4];
#pragma unroll
    for (int j = 0; j < 4; ++j) {
        int e = base + j * 1024 + t;
        ok[j] = e < m;
        bk[j] = 0;
        if (ok[j]) {
            int s_ = src[e], d_ = dst[e];
            v[j] = ((uint)s_ << 16) | (uint)d_;
            bk[j] = d_ >> 8;
            atomicAdd(&hist[bk[j]], 1);
        }
    }
    __syncthreads();
    if (t < 256) {
        int h = hist[t];
        int g = h ? atomicAdd(&bcnt[t], h) : 0;
        cur[t] = t * BCAP + g;
    }
    __syncthreads();
#pragma unroll
    for (int j = 0; j < 4; ++j) {
        if (ok[j]) {
            int pos = atomicAdd(&cur[bk[j]], 1);
            if (pos - bk[j] * BCAP < BCAP)  // statistically unreachable guard
                part[pos] = v[j];
        }
    }
}

// ------- persistent fused: list-build + gather + GEMM1 (h1 in regs) -> grid sync ->
//         BN finalize + BN/ReLU + GEMM2 -> fp32 out.  1024 thr / 16 waves / 2 tiles max.
// Co-residency: GRID_FUSED=500 blocks x 16 waves = 8000 <= 8192 wave slots, LDS 29KB*2
// <= 160KB -> all blocks resident -> counter spin cannot deadlock. The grid-wide sync
// also protects the xb-in-d_out alias: no block reads xb after it, only then is out written.

__global__ __launch_bounds__(1024, 8) void agg_mlp_kernel(const uint* __restrict__ xb,
                                                          const uint* __restrict__ part,
                                                          const int* __restrict__ bcnt,
                                                          const ushort* __restrict__ W1T,
                                                          const ushort* __restrict__ W2T,
                                                          const float* __restrict__ b1,
                                                          const float* __restrict__ b2,
                                                          const float* __restrict__ gamma,
                                                          const float* __restrict__ beta,
                                                          float* __restrict__ bn_sums,
                                                          int* __restrict__ counter,
                                                          float* __restrict__ outp,
                                                          float invn, int n, int nbg) {
    __shared__ __align__(16) ushort hs[64 * D];   // h0 tile (phase A) / h1' tile (phase B), swizzled
    __shared__ ushort lell[64 * ELLW];            // neighbor lists
    __shared__ int lcur[64];
    __shared__ float bs1[D], bs2[D];
    __shared__ float bnl[2 * D];
    __shared__ float ss[2 * D];

    int tid = threadIdx.x;
    int w = tid >> 6, lane = tid & 63;
    int band = w & 3, cq = w >> 2;
    int lrow = lane & 15, lk = lane >> 4;
    char* hsb = (char*)hs;

    if (tid < D) bs1[tid] = b1[tid];
    else if (tid < 2 * D) bs2[tid - D] = b2[tid - D];
    if (tid >= 512 && tid < 768) bnl[tid - 512] = 0.f;

    f32x4 acc[2][2];
#pragma unroll
    for (int s = 0; s < 2; ++s)
#pragma unroll
        for (int f = 0; f < 2; ++f) acc[s][f] = (f32x4){0.f, 0.f, 0.f, 0.f};

    // ---------------- Phase A: per tile, list-build + gather + GEMM1 ----------------
#pragma unroll
    for (int s = 0; s < 2; ++s) {
        int tile = blockIdx.x + s * GRID_FUSED;
        if (tile < nbg) {
            int row0 = tile * 64;
            int bkt = row0 >> 8;
            __syncthreads();  // hs/lell free (also fences preamble LDS writes on s==0)
            if (tid < 64) lcur[tid] = 0;
            __syncthreads();
            int cnt = min(bcnt[bkt], BCAP);
            const uint* pp = part + (size_t)bkt * BCAP;
            for (int i = tid; i < cnt; i += 1024) {
                uint v = pp[i];
                uint r2 = (v & 0xffffu) - (uint)row0;
                if (r2 < 64u) {
                    int sl = atomicAdd(&lcur[(int)r2], 1);
                    sl = min(sl, ELLW - 1);
                    lell[(int)r2 * ELLW + sl] = (ushort)(v >> 16);
                }
            }
            __syncthreads();
            // gather-sum into swizzled LDS tile (wave w owns rows w*4..w*4+4)
            for (int i = 0; i < 4; ++i) {
                int r = w * 4 + i;
                int node = row0 + r;
                float sx = 0.f, sy = 0.f;
                if (node < n) {
                    uint a = xb[node * 64 + lane];
                    sx = blo(a);
                    sy = bhi(a);
                    int deg = min(lcur[r], ELLW);
                    const ushort* lst = &lell[r * ELLW];
                    int e = 0;
                    for (; e + 7 < deg; e += 8) {
                        uint u[8];
#pragma unroll
                        for (int j = 0; j < 8; ++j) u[j] = xb[(int)lst[e + j] * 64 + lane];
#pragma unroll
                        for (int j = 0; j < 8; ++j) { sx += blo(u[j]); sy += bhi(u[j]); }
                    }
                    if (e + 3 < deg) {
                        uint u[4];
#pragma unroll
                        for (int j = 0; j < 4; ++j) u[j] = xb[(int)lst[e + j] * 64 + lane];
#pragma unroll
                        for (int j = 0; j < 4; ++j) { sx += blo(u[j]); sy += bhi(u[j]); }
                        e += 4;
                    }
                    for (; e < deg; ++e) {
                        uint u = xb[(int)lst[e] * 64 + lane];
                        sx += blo(u);
                        sy += bhi(u);
                    }
                }
                uint o = ((uint)f32_to_bf16_rne(sy) << 16) | (uint)f32_to_bf16_rne(sx);
                *(uint*)(hsb + r * 256 +
                         ((((lane >> 2) << 4) ^ ((r & 7) << 4)) | ((lane & 3) << 2))) = o;
            }
            __syncthreads();
            // GEMM1: 16 waves = 4 row-bands x 4 col-quads; B direct from L2-hot W1T
            bf16x8 afr[4];
            int arow = band * 16 + lrow;
#pragma unroll
            for (int t = 0; t < 4; ++t)
                afr[t] = *(const bf16x8*)(hsb + arow * 256 +
                                          ((t * 64 + lk * 16) ^ ((arow & 7) << 4)));
#pragma unroll
            for (int f = 0; f < 2; ++f) {
                int nc = cq * 32 + f * 16 + lrow;
#pragma unroll
                for (int t = 0; t < 4; ++t) {
                    bf16x8 bfr = *(const bf16x8*)(W1T + nc * D + t * 32 + lk * 8);
                    acc[s][f] = __builtin_amdgcn_mfma_f32_16x16x32_bf16(afr[t], bfr, acc[s][f], 0, 0, 0);
                }
            }
            // bias into regs (h1) + BN partials
            int rbase = row0 + band * 16 + lk * 4;
#pragma unroll
            for (int f = 0; f < 2; ++f) {
                int colc = cq * 32 + f * 16 + lrow;
                float bv = bs1[colc];
                float s1 = 0.f, q1 = 0.f;
#pragma unroll
                for (int r = 0; r < 4; ++r) {
                    float v = acc[s][f][r] + bv;
                    acc[s][f][r] = v;
                    int gr = rbase + r;
                    if (gr < n) { s1 += v; q1 += v * v; }
                }
                s1 += __shfl_xor(s1, 16, 64);
                s1 += __shfl_xor(s1, 32, 64);
                q1 += __shfl_xor(q1, 16, 64);
                q1 += __shfl_xor(q1, 32, 64);
                if (lane < 16) {
                    atomicAdd(&bnl[colc], s1);
                    atomicAdd(&bnl[D + colc], q1);
                }
            }
        }
    }

    // ---------------- grid-wide sync ----------------
    __syncthreads();
    if (tid < 2 * D) atomicAdd(&bn_sums[tid], bnl[tid]);
    __threadfence();
    __syncthreads();  // waitcnt before barrier drains the atomics device-wide
    if (tid == 0) {
        atomicAdd(counter, 1);
        while (atomicAdd(counter, 0) < GRID_FUSED) __builtin_amdgcn_s_sleep(2);
    }
    __syncthreads();
    __threadfence();

    // BN finalize (coherent atomic-RMW reads of bn_sums)
    if (tid < 2 * D) ss[tid] = atomicAdd(&bn_sums[tid], 0.0f);
    __syncthreads();
    if (tid < D) {
        float mean = ss[tid] * invn;
        float var = ss[D + tid] * invn - mean * mean;
        float sc = gamma[tid] * rsqrtf(var + 1e-5f);
        ss[tid] = sc;                       // each thread reads/writes only its own pair
        ss[D + tid] = beta[tid] - mean * sc;
    }
    __syncthreads();

    // ---------------- Phase B: BN+ReLU(h1 regs) -> LDS restage -> GEMM2 -> out ----------------
#pragma unroll
    for (int s = 0; s < 2; ++s) {
        int tile = blockIdx.x + s * GRID_FUSED;
        if (tile < nbg) {
            int row0 = tile * 64;
            __syncthreads();  // hs free from previous use
            int rbl = band * 16 + lk * 4;
#pragma unroll
            for (int f = 0; f < 2; ++f) {
                int colc = cq * 32 + f * 16 + lrow;
                float sc = ss[colc], sh = ss[D + colc];
#pragma unroll
                for (int r = 0; r < 4; ++r) {
                    float v = fmaxf(acc[s][f][r] * sc + sh, 0.f);
                    int rl = rbl + r;
                    *(ushort*)(hsb + rl * 256 + ((colc * 2) ^ ((rl & 7) << 4))) = f32_to_bf16_rne(v);
                }
            }
            __syncthreads();
            bf16x8 afr[4];
            int arow = band * 16 + lrow;
#pragma unroll
            for (int t = 0; t < 4; ++t)
                afr[t] = *(const bf16x8*)(hsb + arow * 256 +
                                          ((t * 64 + lk * 16) ^ ((arow & 7) << 4)));
            f32x4 a2[2];
#pragma unroll
            for (int f = 0; f < 2; ++f) a2[f] = (f32x4){0.f, 0.f, 0.f, 0.f};
#pragma unroll
            for (int f = 0; f < 2; ++f) {
                int nc = cq * 32 + f * 16 + lrow;
#pragma unroll
                for (int t = 0; t < 4; ++t) {
                    bf16x8 bfr = *(const bf16x8*)(W2T + nc * D + t * 32 + lk * 8);
                    a2[f] = __builtin_amdgcn_mfma_f32_16x16x32_bf16(afr[t], bfr, a2[f], 0, 0, 0);
                }
            }
            int rbase = row0 + band * 16 + lk * 4;
#pragma unroll
            for (int f = 0; f < 2; ++f) {
                int colc = cq * 32 + f * 16 + lrow;
                float bv = bs2[colc];
#pragma unroll
                for (int r = 0; r < 4; ++r) {
                    int gr = rbase + r;
                    if (gr < n) outp[(size_t)gr * D + colc] = a2[f][r] + bv;
                }
            }
        }
    }
}

// ---------------- launch ----------------

extern "C" void kernel_launch(void* const* d_in, const int* in_sizes, int n_in,
                              void* d_out, int out_size, void* d_ws, size_t ws_size,
                              hipStream_t stream) {
    const float* x = (const float*)d_in[0];
    const int* edge = (const int*)d_in[1];
    const float* W1 = (const float*)d_in[2];
    const float* b1 = (const float*)d_in[3];
    const float* gamma = (const float*)d_in[4];
    const float* beta = (const float*)d_in[5];
    const float* W2 = (const float*)d_in[6];
    const float* b2 = (const float*)d_in[7];

    int n = in_sizes[0] / D;   // 50000
    int m = in_sizes[1] / 2;   // 800000
    const int* src = edge;
    const int* dst = edge + m;

    int nbuck = (n + 255) >> 8;  // 196

    // xb (bf16 pairs of x) lives in d_out's lower half: the grid-wide sync in
    // agg_mlp_kernel guarantees all xb reads complete before any out write.
    uint* xb = (uint*)d_out;

    // workspace layout -- every sub-buffer 64B-aligned
    auto al = [](size_t o) { return (o + 63) & ~(size_t)63; };
    char* ws = (char*)d_ws;
    size_t off = 0;
    uint* part = (uint*)(ws + off);    off = al(off + (size_t)nbuck * BCAP * sizeof(uint));
    int* bcnt = (int*)(ws + off);      off += 768 * sizeof(int);  // bcnt[256]+bn_sums[256]+counter+pad
    float* bn_sums = (float*)(bcnt + 256);
    int* counter = bcnt + 512;
    off = al(off);
    ushort* W1T = (ushort*)(ws + off); off = al(off + (size_t)D * D * sizeof(ushort));
    ushort* W2T = (ushort*)(ws + off); off = al(off + (size_t)D * D * sizeof(ushort));

    int nbx = (n * 64 + 1023) / 1024;        // 3125
    int nbs = (m + 4095) / 4096;             // 196
    int nbg = (n + 63) / 64;                 // 782

    zero_kernel<<<1, 768, 0, stream>>>(bcnt);  // zeroes bcnt + bn_sums + counter
    prep_scatter_kernel<<<nbx + 32 + nbs, 1024, 0, stream>>>((const float2*)x, W1, W2, src, dst,
                                                             xb, W1T, W2T, part, bcnt, n * 64, m, nbx);
    agg_mlp_kernel<<<GRID_FUSED, 1024, 0, stream>>>(xb, part, bcnt, W1T, W2T, b1, b2, gamma, beta,
                                                    bn_sums, counter, (float*)d_out,
                                                    1.0f / (float)n, n, nbg);
}

// Round 15
// 104.565 us; speedup vs baseline: 3.6605x; 3.6605x over previous
//
#include <hip/hip_runtime.h>
#include <hip/hip_bf16.h>

#define D 128    // feature dim (both in and out)
#define ELLW 64  // fixed ELL width; Poisson(16) max degree over 50K nodes << 64
#define BCAP 8192  // edges per 256-node bucket region; E[edges]=4096, +64 sigma

typedef short bf16x8 __attribute__((ext_vector_type(8)));
typedef float f32x4 __attribute__((ext_vector_type(4)));

__device__ __forceinline__ ushort f32_to_bf16_rne(float f) {
    uint b = __float_as_uint(f);
    b += 0x7fffu + ((b >> 16) & 1u);
    return (ushort)(b >> 16);
}
__device__ __forceinline__ float bf16_bits_to_f32(ushort u) {
    return __uint_as_float(((uint)u) << 16);
}
__device__ __forceinline__ float blo(uint u) { return __uint_as_float(u << 16); }
__device__ __forceinline__ float bhi(uint u) { return __uint_as_float(u & 0xffff0000u); }

// ---------------- tiny zero: bcnt[256] + bn_sums[256] (contiguous) ----------------

__global__ __launch_bounds__(512) void zero_kernel(int* __restrict__ p) {
    p[threadIdx.x] = 0;
}

// ------- fused prep+scatter: x->bf16 (into d_out!) | W^T bf16 | bucket scatter -------

__global__ __launch_bounds__(1024) void prep_scatter_kernel(const float2* __restrict__ x2,
                                                            const float* __restrict__ W1,
                                                            const float* __restrict__ W2,
                                                            const int* __restrict__ src,
                                                            const int* __restrict__ dst,
                                                            uint* __restrict__ xb,
                                                            ushort* __restrict__ W1T,
                                                            ushort* __restrict__ W2T,
                                                            uint* __restrict__ part,
                                                            int* __restrict__ bcnt,
                                                            int nhalf, int m, int nbx) {
    int b = blockIdx.x, t = threadIdx.x;
    if (b < nbx) {
        int i = b * 1024 + t;
        if (i < nhalf) {
            float2 v = x2[i];
            xb[i] = ((uint)f32_to_bf16_rne(v.y) << 16) | (uint)f32_to_bf16_rne(v.x);
        }
        return;
    }
    if (b < nbx + 32) {
        int wb = b - nbx;
        const float* W = (wb < 16) ? W1 : W2;
        ushort* WT = (wb < 16) ? W1T : W2T;
        int q = wb & 15;
        int nrow = q * 8 + (t >> 7);
        int k = t & 127;
        WT[nrow * D + k] = f32_to_bf16_rne(W[k * D + nrow]);
        return;
    }
    __shared__ int hist[256];
    __shared__ int cur[256];
    if (t < 256) hist[t] = 0;
    __syncthreads();

    int base = (b - nbx - 32) * 4096;
    uint v[4];
    int bk[4];
    bool ok[4];
#pragma unroll
    for (int j = 0; j < 4; ++j) {
        int e = base + j * 1024 + t;
        ok[j] = e < m;
        bk[j] = 0;
        if (ok[j]) {
            int s_ = src[e], d_ = dst[e];
            v[j] = ((uint)s_ << 16) | (uint)d_;
            bk[j] = d_ >> 8;
            atomicAdd(&hist[bk[j]], 1);
        }
    }
    __syncthreads();
    if (t < 256) {
        int h = hist[t];
        int g = h ? atomicAdd(&bcnt[t], h) : 0;
        cur[t] = t * BCAP + g;
    }
    __syncthreads();
#pragma unroll
    for (int j = 0; j < 4; ++j) {
        if (ok[j]) {
            int pos = atomicAdd(&cur[bk[j]], 1);
            if (pos - bk[j] * BCAP < BCAP)  // statistically unreachable guard
                part[pos] = v[j];
        }
    }
}

// ------- fused list-build + aggregate + GEMM1 + BN stats (1024 threads / 16 waves) -------
// Block = 64 output rows. Phase 1: rebuild the block's 64 neighbor lists in LDS from its
// bucket's packed run. Phase 2: wave w gathers rows w*4..w*4+4 into the swizzled LDS
// tile. Phase 3: 16 waves = 4 row-bands x 4 col-quads; acc[2] each; B direct from L2-hot
// W1T. Epilogue: bf16 h1 store + per-channel BN sum/sumsq.
// NOTE (r14 lesson): no grid-wide spin sync here — spin atomics poison the L2 fabric
// that the request-rate-bound gather depends on (362us vs 58us).

__global__ __launch_bounds__(1024) void agg_gemm1_kernel(const uint* __restrict__ xb,
                                                         const uint* __restrict__ part,
                                                         const int* __restrict__ bcnt,
                                                         const ushort* __restrict__ W1T,
                                                         const float* __restrict__ bias,
                                                         ushort* __restrict__ h1b,
                                                         float* __restrict__ bn_sums,
                                                         int n) {
    __shared__ __align__(16) ushort hs[64 * D];   // input tile, swizzled
    __shared__ ushort lell[64 * ELLW];            // neighbor lists
    __shared__ int lcur[64];
    __shared__ float bs[D];
    __shared__ float bnl[2 * D];

    int tid = threadIdx.x;
    int row0 = blockIdx.x * 64;
    int bkt = row0 >> 8;
    if (tid < 64) lcur[tid] = 0;
    if (tid >= 128 && tid < 256) bs[tid - 128] = bias[tid - 128];
    if (tid >= 256 && tid < 512) bnl[tid - 256] = 0.f;
    __syncthreads();

    // Phase 1: list build from bucket's packed run
    int cnt = min(bcnt[bkt], BCAP);
    const uint* pp = part + (size_t)bkt * BCAP;
    for (int i = tid; i < cnt; i += 1024) {
        uint v = pp[i];
        uint r2 = (v & 0xffffu) - (uint)row0;
        if (r2 < 64u) {
            int s = atomicAdd(&lcur[(int)r2], 1);
            s = min(s, ELLW - 1);
            lell[(int)r2 * ELLW + s] = (ushort)(v >> 16);
        }
    }
    __syncthreads();

    // Phase 2: gather-sum into swizzled LDS tile (wave w owns rows w*4..w*4+4)
    int w = tid >> 6, lane = tid & 63;
    char* hsb = (char*)hs;
    for (int i = 0; i < 4; ++i) {
        int r = w * 4 + i;
        int node = row0 + r;
        float sx = 0.f, sy = 0.f;
        if (node < n) {
            uint a = xb[node * 64 + lane];
            sx = blo(a);
            sy = bhi(a);
            int deg = min(lcur[r], ELLW);
            const ushort* lst = &lell[r * ELLW];
            int e = 0;
            for (; e + 7 < deg; e += 8) {
                uint u[8];
#pragma unroll
                for (int j = 0; j < 8; ++j) u[j] = xb[(int)lst[e + j] * 64 + lane];
#pragma unroll
                for (int j = 0; j < 8; ++j) { sx += blo(u[j]); sy += bhi(u[j]); }
            }
            if (e + 3 < deg) {
                uint u[4];
#pragma unroll
                for (int j = 0; j < 4; ++j) u[j] = xb[(int)lst[e + j] * 64 + lane];
#pragma unroll
                for (int j = 0; j < 4; ++j) { sx += blo(u[j]); sy += bhi(u[j]); }
                e += 4;
            }
            for (; e < deg; ++e) {
                uint u = xb[(int)lst[e] * 64 + lane];
                sx += blo(u);
                sy += bhi(u);
            }
        }
        uint o = ((uint)f32_to_bf16_rne(sy) << 16) | (uint)f32_to_bf16_rne(sx);
        // swizzled 4B store: chunk=(lane>>2), within-chunk=(lane&3)*4, XOR on chunk bits
        *(uint*)(hsb + r * 256 + ((((lane >> 2) << 4) ^ ((r & 7) << 4)) | ((lane & 3) << 2))) = o;
    }
    __syncthreads();

    // Phase 3: MFMA. 16 waves = 4 row-bands (w&3) x 4 col-quads (w>>2).
    int band = w & 3, cq = w >> 2;
    int lrow = lane & 15, lk = lane >> 4;

    f32x4 acc[2];
#pragma unroll
    for (int f = 0; f < 2; ++f) acc[f] = (f32x4){0.f, 0.f, 0.f, 0.f};

    bf16x8 afr[4];
    int arow = band * 16 + lrow;
#pragma unroll
    for (int t = 0; t < 4; ++t)
        afr[t] = *(const bf16x8*)(hsb + arow * 256 + ((t * 64 + lk * 16) ^ ((arow & 7) << 4)));

#pragma unroll
    for (int f = 0; f < 2; ++f) {
        int nc = cq * 32 + f * 16 + lrow;
#pragma unroll
        for (int t = 0; t < 4; ++t) {
            bf16x8 bfr = *(const bf16x8*)(W1T + nc * D + t * 32 + lk * 8);
            acc[f] = __builtin_amdgcn_mfma_f32_16x16x32_bf16(afr[t], bfr, acc[f], 0, 0, 0);
        }
    }

    // epilogue: D[row=lk*4+r][col=lrow]; store bf16 h1 + BN stats
    int rbase = row0 + band * 16 + lk * 4;
#pragma unroll
    for (int f = 0; f < 2; ++f) {
        int colc = cq * 32 + f * 16 + lrow;
        float bv = bs[colc];
        float s = 0.f, q = 0.f;
#pragma unroll
        for (int r = 0; r < 4; ++r) {
            int gr = rbase + r;
            if (gr < n) {
                float v = acc[f][r] + bv;
                h1b[(size_t)gr * D + colc] = f32_to_bf16_rne(v);
                s += v;
                q += v * v;
            }
        }
        s += __shfl_xor(s, 16, 64);
        s += __shfl_xor(s, 32, 64);
        q += __shfl_xor(q, 16, 64);
        q += __shfl_xor(q, 32, 64);
        if (lane < 16) {
            atomicAdd(&bnl[colc], s);
            atomicAdd(&bnl[D + colc], q);
        }
    }
    __syncthreads();
    if (tid < 2 * D) atomicAdd(&bn_sums[tid], bnl[tid]);
}

// ---------------- GEMM2: out = relu(BN(h1)) @ W2 + b2 (fp32 out) ----------------
// 64 rows x 128 cols per 256-thread block. Input tile staged+swizzled in LDS;
// B-fragments read DIRECT from L2-hot W2T (r14 port: saves 32KB LDS + a barrier).
// BN scale/shift derived from bn_sums in the preamble (no finalize dispatch).

__global__ __launch_bounds__(256) void gemm2_kernel(const ushort* __restrict__ inb,
                                                    const ushort* __restrict__ WT,
                                                    const float* __restrict__ bias,
                                                    float* __restrict__ outp,
                                                    const float* __restrict__ gamma,
                                                    const float* __restrict__ beta,
                                                    const float* __restrict__ bn_sums,
                                                    float invn, int N) {
    __shared__ __align__(16) ushort hs[64 * D];   // input tile, swizzled
    __shared__ float ss[2 * D];
    __shared__ float bs[D];

    int tid = threadIdx.x;
    int row0 = blockIdx.x * 64;
    if (tid < D) bs[tid] = bias[tid];
    if (tid < D) {
        float mean = bn_sums[tid] * invn;
        float var = bn_sums[D + tid] * invn - mean * mean;
        float sc = gamma[tid] * rsqrtf(var + 1e-5f);
        ss[tid] = sc;
        ss[D + tid] = beta[tid] - mean * sc;
    }
    // ss/bs consumed by OTHER threads below -> fence.
    __syncthreads();

    char* hsb = (char*)hs;

#pragma unroll
    for (int it = 0; it < 4; ++it) {
        int c = it * 256 + tid;
        int row = c >> 4, k8 = c & 15;
        int gr = row0 + row;
        bf16x8 v;
        if (gr < N) {
            v = *(const bf16x8*)(inb + (size_t)gr * D + k8 * 8);
        } else {
#pragma unroll
            for (int j = 0; j < 8; ++j) v[j] = 0;
        }
#pragma unroll
        for (int j = 0; j < 8; ++j) {
            int k = k8 * 8 + j;
            float f = bf16_bits_to_f32((ushort)v[j]);
            f = fmaxf(f * ss[k] + ss[D + k], 0.f);
            v[j] = (short)f32_to_bf16_rne(f);
        }
        *(bf16x8*)(hsb + row * 256 + ((k8 * 16) ^ ((row & 7) << 4))) = v;
    }
    __syncthreads();

    int w = tid >> 6, l = tid & 63;
    int lrow = l & 15, lk = l >> 4;

    f32x4 acc[8];
#pragma unroll
    for (int f = 0; f < 8; ++f) acc[f] = (f32x4){0.f, 0.f, 0.f, 0.f};

    bf16x8 afr[4];
    int arow = w * 16 + lrow;
#pragma unroll
    for (int t = 0; t < 4; ++t)
        afr[t] = *(const bf16x8*)(hsb + arow * 256 + ((t * 64 + lk * 16) ^ ((arow & 7) << 4)));

#pragma unroll
    for (int f = 0; f < 8; ++f) {
        int nc = f * 16 + lrow;
#pragma unroll
        for (int t = 0; t < 4; ++t) {
            bf16x8 bfr = *(const bf16x8*)(WT + nc * D + t * 32 + lk * 8);
            acc[f] = __builtin_amdgcn_mfma_f32_16x16x32_bf16(afr[t], bfr, acc[f], 0, 0, 0);
        }
    }

    int rbase = row0 + w * 16 + lk * 4;
#pragma unroll
    for (int f = 0; f < 8; ++f) {
        int colc = f * 16 + lrow;
        float bv = bs[colc];
#pragma unroll
        for (int r = 0; r < 4; ++r) {
            int gr = rbase + r;
            if (gr < N) outp[(size_t)gr * D + colc] = acc[f][r] + bv;
        }
    }
}

// ---------------- launch ----------------

extern "C" void kernel_launch(void* const* d_in, const int* in_sizes, int n_in,
                              void* d_out, int out_size, void* d_ws, size_t ws_size,
                              hipStream_t stream) {
    const float* x = (const float*)d_in[0];
    const int* edge = (const int*)d_in[1];
    const float* W1 = (const float*)d_in[2];
    const float* b1 = (const float*)d_in[3];
    const float* gamma = (const float*)d_in[4];
    const float* beta = (const float*)d_in[5];
    const float* W2 = (const float*)d_in[6];
    const float* b2 = (const float*)d_in[7];

    int n = in_sizes[0] / D;   // 50000
    int m = in_sizes[1] / 2;   // 800000
    const int* src = edge;
    const int* dst = edge + m;

    int nbuck = (n + 255) >> 8;  // 196

    // xb (bf16 pairs of x) lives in d_out's lower half: dead before gemm2 overwrites d_out.
    uint* xb = (uint*)d_out;

    // workspace layout -- every sub-buffer 64B-aligned
    auto al = [](size_t o) { return (o + 63) & ~(size_t)63; };
    char* ws = (char*)d_ws;
    size_t off = 0;
    ushort* h1b = (ushort*)(ws + off); off = al(off + (size_t)n * D * sizeof(ushort));
    uint* part = (uint*)(ws + off);    off = al(off + (size_t)nbuck * BCAP * sizeof(uint));
    int* bcnt = (int*)(ws + off);      off += 256 * sizeof(int);            // keep bn_sums adjacent:
    float* bn_sums = (float*)(ws + off); off = al(off + 2 * D * sizeof(float)); // one zero_kernel covers both
    ushort* W1T = (ushort*)(ws + off); off = al(off + (size_t)D * D * sizeof(ushort));
    ushort* W2T = (ushort*)(ws + off); off = al(off + (size_t)D * D * sizeof(ushort));

    int nbx = (n * 64 + 1023) / 1024;        // 3125
    int nbs = (m + 4095) / 4096;             // 196
    int nbg = (n + 63) / 64;                 // 782

    zero_kernel<<<1, 512, 0, stream>>>(bcnt);  // zeroes bcnt[256] + bn_sums[256]
    prep_scatter_kernel<<<nbx + 32 + nbs, 1024, 0, stream>>>((const float2*)x, W1, W2, src, dst,
                                                             xb, W1T, W2T, part, bcnt, n * 64, m, nbx);
    agg_gemm1_kernel<<<nbg, 1024, 0, stream>>>(xb, part, bcnt, W1T, b1, h1b, bn_sums, n);
    gemm2_kernel<<<nbg, 256, 0, stream>>>(h1b, W2T, b2, (float*)d_out, gamma, beta,
                                          bn_sums, 1.0f / (float)n, n);
}

// Round 16
// 98.243 us; speedup vs baseline: 3.8961x; 1.0643x over previous
//
#include <hip/hip_runtime.h>
#include <hip/hip_bf16.h>

#define D 128    // feature dim (both in and out)
#define ELLW 64  // fixed ELL width; Poisson(16) max degree over 50K nodes << 64
#define BCAP 8192  // edges per 256-node bucket region; E[edges]=4096, +64 sigma

typedef short bf16x8 __attribute__((ext_vector_type(8)));
typedef float f32x4 __attribute__((ext_vector_type(4)));

__device__ __forceinline__ ushort f32_to_bf16_rne(float f) {
    uint b = __float_as_uint(f);
    b += 0x7fffu + ((b >> 16) & 1u);
    return (ushort)(b >> 16);
}
__device__ __forceinline__ float bf16_bits_to_f32(ushort u) {
    return __uint_as_float(((uint)u) << 16);
}
__device__ __forceinline__ float blo(uint u) { return __uint_as_float(u << 16); }
__device__ __forceinline__ float bhi(uint u) { return __uint_as_float(u & 0xffff0000u); }

// ---------------- tiny zero: bcnt[256] + bn_sums[256] (contiguous) ----------------

__global__ __launch_bounds__(512) void zero_kernel(int* __restrict__ p) {
    p[threadIdx.x] = 0;
}

// ------- fused prep+scatter: x->bf16 (into d_out!) | W^T bf16 | bucket scatter -------

__global__ __launch_bounds__(1024) void prep_scatter_kernel(const float2* __restrict__ x2,
                                                            const float* __restrict__ W1,
                                                            const float* __restrict__ W2,
                                                            const int* __restrict__ src,
                                                            const int* __restrict__ dst,
                                                            uint* __restrict__ xb,
                                                            ushort* __restrict__ W1T,
                                                            ushort* __restrict__ W2T,
                                                            uint* __restrict__ part,
                                                            int* __restrict__ bcnt,
                                                            int nhalf, int m, int nbx) {
    int b = blockIdx.x, t = threadIdx.x;
    if (b < nbx) {
        int i = b * 1024 + t;
        if (i < nhalf) {
            float2 v = x2[i];
            xb[i] = ((uint)f32_to_bf16_rne(v.y) << 16) | (uint)f32_to_bf16_rne(v.x);
        }
        return;
    }
    if (b < nbx + 32) {
        int wb = b - nbx;
        const float* W = (wb < 16) ? W1 : W2;
        ushort* WT = (wb < 16) ? W1T : W2T;
        int q = wb & 15;
        int nrow = q * 8 + (t >> 7);
        int k = t & 127;
        WT[nrow * D + k] = f32_to_bf16_rne(W[k * D + nrow]);
        return;
    }
    __shared__ int hist[256];
    __shared__ int cur[256];
    if (t < 256) hist[t] = 0;
    __syncthreads();

    int base = (b - nbx - 32) * 4096;
    uint v[4];
    int bk[4];
    bool ok[4];
#pragma unroll
    for (int j = 0; j < 4; ++j) {
        int e = base + j * 1024 + t;
        ok[j] = e < m;
        bk[j] = 0;
        if (ok[j]) {
            int s_ = src[e], d_ = dst[e];
            v[j] = ((uint)s_ << 16) | (uint)d_;
            bk[j] = d_ >> 8;
            atomicAdd(&hist[bk[j]], 1);
        }
    }
    __syncthreads();
    if (t < 256) {
        int h = hist[t];
        int g = h ? atomicAdd(&bcnt[t], h) : 0;
        cur[t] = t * BCAP + g;
    }
    __syncthreads();
#pragma unroll
    for (int j = 0; j < 4; ++j) {
        if (ok[j]) {
            int pos = atomicAdd(&cur[bk[j]], 1);
            if (pos - bk[j] * BCAP < BCAP)  // statistically unreachable guard
                part[pos] = v[j];
        }
    }
}

// ------- fused list-build + aggregate + GEMM1 + BN stats (1024 threads / 16 waves) -------
// Block = 64 output rows. Phase 1: rebuild the block's 64 neighbor lists in LDS from its
// bucket's packed run. Phase 2: wave w gathers rows w*4..w*4+4 into the swizzled LDS
// tile. Phase 3: 16 waves = 4 row-bands x 4 col-quads; acc[2] each; B direct from L2-hot
// W1T (hidden under the latency-bound gather phase of co-resident blocks).
// NOTE (r14 lesson): no grid-wide spin sync — spin atomics poison the L2 fabric the
// request-rate-bound gather depends on (362us vs 58us).

__global__ __launch_bounds__(1024) void agg_gemm1_kernel(const uint* __restrict__ xb,
                                                         const uint* __restrict__ part,
                                                         const int* __restrict__ bcnt,
                                                         const ushort* __restrict__ W1T,
                                                         const float* __restrict__ bias,
                                                         ushort* __restrict__ h1b,
                                                         float* __restrict__ bn_sums,
                                                         int n) {
    __shared__ __align__(16) ushort hs[64 * D];   // input tile, swizzled
    __shared__ ushort lell[64 * ELLW];            // neighbor lists
    __shared__ int lcur[64];
    __shared__ float bs[D];
    __shared__ float bnl[2 * D];

    int tid = threadIdx.x;
    int row0 = blockIdx.x * 64;
    int bkt = row0 >> 8;
    if (tid < 64) lcur[tid] = 0;
    if (tid >= 128 && tid < 256) bs[tid - 128] = bias[tid - 128];
    if (tid >= 256 && tid < 512) bnl[tid - 256] = 0.f;
    __syncthreads();

    // Phase 1: list build from bucket's packed run
    int cnt = min(bcnt[bkt], BCAP);
    const uint* pp = part + (size_t)bkt * BCAP;
    for (int i = tid; i < cnt; i += 1024) {
        uint v = pp[i];
        uint r2 = (v & 0xffffu) - (uint)row0;
        if (r2 < 64u) {
            int s = atomicAdd(&lcur[(int)r2], 1);
            s = min(s, ELLW - 1);
            lell[(int)r2 * ELLW + s] = (ushort)(v >> 16);
        }
    }
    __syncthreads();

    // Phase 2: gather-sum into swizzled LDS tile (wave w owns rows w*4..w*4+4)
    int w = tid >> 6, lane = tid & 63;
    char* hsb = (char*)hs;
    for (int i = 0; i < 4; ++i) {
        int r = w * 4 + i;
        int node = row0 + r;
        float sx = 0.f, sy = 0.f;
        if (node < n) {
            uint a = xb[node * 64 + lane];
            sx = blo(a);
            sy = bhi(a);
            int deg = min(lcur[r], ELLW);
            const ushort* lst = &lell[r * ELLW];
            int e = 0;
            for (; e + 7 < deg; e += 8) {
                uint u[8];
#pragma unroll
                for (int j = 0; j < 8; ++j) u[j] = xb[(int)lst[e + j] * 64 + lane];
#pragma unroll
                for (int j = 0; j < 8; ++j) { sx += blo(u[j]); sy += bhi(u[j]); }
            }
            if (e + 3 < deg) {
                uint u[4];
#pragma unroll
                for (int j = 0; j < 4; ++j) u[j] = xb[(int)lst[e + j] * 64 + lane];
#pragma unroll
                for (int j = 0; j < 4; ++j) { sx += blo(u[j]); sy += bhi(u[j]); }
                e += 4;
            }
            for (; e < deg; ++e) {
                uint u = xb[(int)lst[e] * 64 + lane];
                sx += blo(u);
                sy += bhi(u);
            }
        }
        uint o = ((uint)f32_to_bf16_rne(sy) << 16) | (uint)f32_to_bf16_rne(sx);
        // swizzled 4B store: chunk=(lane>>2), within-chunk=(lane&3)*4, XOR on chunk bits
        *(uint*)(hsb + r * 256 + ((((lane >> 2) << 4) ^ ((r & 7) << 4)) | ((lane & 3) << 2))) = o;
    }
    __syncthreads();

    // Phase 3: MFMA. 16 waves = 4 row-bands (w&3) x 4 col-quads (w>>2).
    int band = w & 3, cq = w >> 2;
    int lrow = lane & 15, lk = lane >> 4;

    f32x4 acc[2];
#pragma unroll
    for (int f = 0; f < 2; ++f) acc[f] = (f32x4){0.f, 0.f, 0.f, 0.f};

    bf16x8 afr[4];
    int arow = band * 16 + lrow;
#pragma unroll
    for (int t = 0; t < 4; ++t)
        afr[t] = *(const bf16x8*)(hsb + arow * 256 + ((t * 64 + lk * 16) ^ ((arow & 7) << 4)));

#pragma unroll
    for (int f = 0; f < 2; ++f) {
        int nc = cq * 32 + f * 16 + lrow;
#pragma unroll
        for (int t = 0; t < 4; ++t) {
            bf16x8 bfr = *(const bf16x8*)(W1T + nc * D + t * 32 + lk * 8);
            acc[f] = __builtin_amdgcn_mfma_f32_16x16x32_bf16(afr[t], bfr, acc[f], 0, 0, 0);
        }
    }

    // epilogue: D[row=lk*4+r][col=lrow]; store bf16 h1 + BN stats
    int rbase = row0 + band * 16 + lk * 4;
#pragma unroll
    for (int f = 0; f < 2; ++f) {
        int colc = cq * 32 + f * 16 + lrow;
        float bv = bs[colc];
        float s = 0.f, q = 0.f;
#pragma unroll
        for (int r = 0; r < 4; ++r) {
            int gr = rbase + r;
            if (gr < n) {
                float v = acc[f][r] + bv;
                h1b[(size_t)gr * D + colc] = f32_to_bf16_rne(v);
                s += v;
                q += v * v;
            }
        }
        s += __shfl_xor(s, 16, 64);
        s += __shfl_xor(s, 32, 64);
        q += __shfl_xor(q, 16, 64);
        q += __shfl_xor(q, 32, 64);
        if (lane < 16) {
            atomicAdd(&bnl[colc], s);
            atomicAdd(&bnl[D + colc], q);
        }
    }
    __syncthreads();
    if (tid < 2 * D) atomicAdd(&bn_sums[tid], bnl[tid]);
}

// ---------------- GEMM2: out = relu(BN(h1)) @ W2 + b2 (fp32 out) ----------------
// r13-exact: 64 rows x 128 cols per 256-thread block; BOTH input tile and W^T tile
// staged+swizzled in LDS (direct-global B-fragments regressed 6us in r15 — 16
// line-touches/instr with nothing to hide them). BN scale/shift derived in preamble.

__global__ __launch_bounds__(256) void gemm2_kernel(const ushort* __restrict__ inb,
                                                    const ushort* __restrict__ WT,
                                                    const float* __restrict__ bias,
                                                    float* __restrict__ outp,
                                                    const float* __restrict__ gamma,
                                                    const float* __restrict__ beta,
                                                    const float* __restrict__ bn_sums,
                                                    float invn, int N) {
    __shared__ __align__(16) ushort hs[64 * D];   // input tile, swizzled
    __shared__ __align__(16) ushort wt[D * D];    // W^T tile, swizzled
    __shared__ float ss[2 * D];
    __shared__ float bs[D];

    int tid = threadIdx.x;
    int row0 = blockIdx.x * 64;
    if (tid < D) bs[tid] = bias[tid];
    if (tid < D) {
        float mean = bn_sums[tid] * invn;
        float var = bn_sums[D + tid] * invn - mean * mean;
        float sc = gamma[tid] * rsqrtf(var + 1e-5f);
        ss[tid] = sc;
        ss[D + tid] = beta[tid] - mean * sc;
    }
    // ss/bs consumed by OTHER threads below -> fence.
    __syncthreads();

    char* hsb = (char*)hs;
    char* wtb = (char*)wt;

#pragma unroll
    for (int it = 0; it < 8; ++it) {
        int c = it * 256 + tid;
        int wn = c >> 4, k8 = c & 15;
        bf16x8 v = *(const bf16x8*)(WT + wn * D + k8 * 8);
        *(bf16x8*)(wtb + wn * 256 + ((k8 * 16) ^ ((wn & 7) << 4))) = v;
    }
#pragma unroll
    for (int it = 0; it < 4; ++it) {
        int c = it * 256 + tid;
        int row = c >> 4, k8 = c & 15;
        int gr = row0 + row;
        bf16x8 v;
        if (gr < N) {
            v = *(const bf16x8*)(inb + (size_t)gr * D + k8 * 8);
        } else {
#pragma unroll
            for (int j = 0; j < 8; ++j) v[j] = 0;
        }
#pragma unroll
        for (int j = 0; j < 8; ++j) {
            int k = k8 * 8 + j;
            float f = bf16_bits_to_f32((ushort)v[j]);
            f = fmaxf(f * ss[k] + ss[D + k], 0.f);
            v[j] = (short)f32_to_bf16_rne(f);
        }
        *(bf16x8*)(hsb + row * 256 + ((k8 * 16) ^ ((row & 7) << 4))) = v;
    }
    __syncthreads();

    int w = tid >> 6, l = tid & 63;
    int lrow = l & 15, lk = l >> 4;

    f32x4 acc[8];
#pragma unroll
    for (int f = 0; f < 8; ++f) acc[f] = (f32x4){0.f, 0.f, 0.f, 0.f};

    bf16x8 afr[4];
    int arow = w * 16 + lrow;
#pragma unroll
    for (int t = 0; t < 4; ++t)
        afr[t] = *(const bf16x8*)(hsb + arow * 256 + ((t * 64 + lk * 16) ^ ((arow & 7) << 4)));

#pragma unroll
    for (int f = 0; f < 8; ++f) {
        int nc = f * 16 + lrow;
#pragma unroll
        for (int t = 0; t < 4; ++t) {
            bf16x8 bfr = *(const bf16x8*)(wtb + nc * 256 + ((t * 64 + lk * 16) ^ ((nc & 7) << 4)));
            acc[f] = __builtin_amdgcn_mfma_f32_16x16x32_bf16(afr[t], bfr, acc[f], 0, 0, 0);
        }
    }

    int rbase = row0 + w * 16 + lk * 4;
#pragma unroll
    for (int f = 0; f < 8; ++f) {
        int colc = f * 16 + lrow;
        float bv = bs[colc];
#pragma unroll
        for (int r = 0; r < 4; ++r) {
            int gr = rbase + r;
            if (gr < N) outp[(size_t)gr * D + colc] = acc[f][r] + bv;
        }
    }
}

// ---------------- launch ----------------

extern "C" void kernel_launch(void* const* d_in, const int* in_sizes, int n_in,
                              void* d_out, int out_size, void* d_ws, size_t ws_size,
                              hipStream_t stream) {
    const float* x = (const float*)d_in[0];
    const int* edge = (const int*)d_in[1];
    const float* W1 = (const float*)d_in[2];
    const float* b1 = (const float*)d_in[3];
    const float* gamma = (const float*)d_in[4];
    const float* beta = (const float*)d_in[5];
    const float* W2 = (const float*)d_in[6];
    const float* b2 = (const float*)d_in[7];

    int n = in_sizes[0] / D;   // 50000
    int m = in_sizes[1] / 2;   // 800000
    const int* src = edge;
    const int* dst = edge + m;

    int nbuck = (n + 255) >> 8;  // 196

    // xb (bf16 pairs of x) lives in d_out's lower half: dead before gemm2 overwrites d_out.
    uint* xb = (uint*)d_out;

    // workspace layout -- every sub-buffer 64B-aligned
    auto al = [](size_t o) { return (o + 63) & ~(size_t)63; };
    char* ws = (char*)d_ws;
    size_t off = 0;
    ushort* h1b = (ushort*)(ws + off); off = al(off + (size_t)n * D * sizeof(ushort));
    uint* part = (uint*)(ws + off);    off = al(off + (size_t)nbuck * BCAP * sizeof(uint));
    int* bcnt = (int*)(ws + off);      off += 256 * sizeof(int);            // keep bn_sums adjacent:
    float* bn_sums = (float*)(ws + off); off = al(off + 2 * D * sizeof(float)); // one zero_kernel covers both
    ushort* W1T = (ushort*)(ws + off); off = al(off + (size_t)D * D * sizeof(ushort));
    ushort* W2T = (ushort*)(ws + off); off = al(off + (size_t)D * D * sizeof(ushort));

    int nbx = (n * 64 + 1023) / 1024;        // 3125
    int nbs = (m + 4095) / 4096;             // 196
    int nbg = (n + 63) / 64;                 // 782

    zero_kernel<<<1, 512, 0, stream>>>(bcnt);  // zeroes bcnt[256] + bn_sums[256]
    prep_scatter_kernel<<<nbx + 32 + nbs, 1024, 0, stream>>>((const float2*)x, W1, W2, src, dst,
                                                             xb, W1T, W2T, part, bcnt, n * 64, m, nbx);
    agg_gemm1_kernel<<<nbg, 1024, 0, stream>>>(xb, part, bcnt, W1T, b1, h1b, bn_sums, n);
    gemm2_kernel<<<nbg, 256, 0, stream>>>(h1b, W2T, b2, (float*)d_out, gamma, beta,
                                          bn_sums, 1.0f / (float)n, n);
}